// Round 6
// baseline (377.582 us; speedup 1.0000x reference)
//
#include <hip/hip_runtime.h>
#include <hip/hip_bf16.h>

#define N_NODES 100000
#define N_RELS  4
#define N_EDGES 250000
#define TOTAL_E (N_RELS * N_EDGES)
#define NR      (N_RELS * N_NODES)
#define D       128

typedef __attribute__((ext_vector_type(8))) short bf16x8;
typedef __attribute__((ext_vector_type(4))) float f32x4;

__device__ __forceinline__ float b2f(short u) {
    unsigned int x = ((unsigned int)(unsigned short)u) << 16;
    return __builtin_bit_cast(float, x);
}
__device__ __forceinline__ unsigned short f2b(float f) {
    unsigned int u = __builtin_bit_cast(unsigned int, f);
    return (unsigned short)((u + 0x7fffu + ((u >> 16) & 1u)) >> 16);  // RNE
}

// ---------------------------------------------------------------------------
// prep: convert_x (blocks [0,6250)), convert_w ([6250,6570)), hist (rest).
// ---------------------------------------------------------------------------
#define PREP_X_BLKS 6250
#define PREP_W_BLKS 320
#define PREP_H_BLKS 3907
__global__ __launch_bounds__(256) void prep_kernel(
    const float* __restrict__ x, const float* __restrict__ weight,
    const float* __restrict__ loop_w, const int* __restrict__ dst,
    unsigned short* __restrict__ xb, unsigned short* __restrict__ wT,
    int* __restrict__ deg)
{
    int b = blockIdx.x, t = threadIdx.x;
    if (b < PREP_X_BLKS) {
        int i = b * 256 + t;                       // < 1,600,000 exactly
        float4 v0 = *reinterpret_cast<const float4*>(x + (size_t)i * 8);
        float4 v1 = *reinterpret_cast<const float4*>(x + (size_t)i * 8 + 4);
        bf16x8 o;
        o[0] = (short)f2b(v0.x); o[1] = (short)f2b(v0.y);
        o[2] = (short)f2b(v0.z); o[3] = (short)f2b(v0.w);
        o[4] = (short)f2b(v1.x); o[5] = (short)f2b(v1.y);
        o[6] = (short)f2b(v1.z); o[7] = (short)f2b(v1.w);
        *reinterpret_cast<bf16x8*>(xb + (size_t)i * 8) = o;
    } else if (b < PREP_X_BLKS + PREP_W_BLKS) {
        int i = (b - PREP_X_BLKS) * 256 + t;       // < 81920 exactly
        int mat = i >> 14;
        int n   = (i >> 7) & 127;
        int k   = i & 127;
        const float* srcm = (mat < 4) ? (weight + (size_t)mat * D * D) : loop_w;
        wT[i] = f2b(srcm[k * D + n]);
    } else {
        int i = (b - PREP_X_BLKS - PREP_W_BLKS) * 256 + t;
        if (i < TOTAL_E) {
            int rel = i / N_EDGES;
            atomicAdd(&deg[rel * N_NODES + dst[i]], 1);
        }
    }
}

// ---------------------------------------------------------------------------
// scan1: per-1024-chunk exclusive scan, chunk totals -> aux
// ---------------------------------------------------------------------------
__global__ __launch_bounds__(256) void scan1_kernel(
    const int* __restrict__ in, int* __restrict__ out,
    int* __restrict__ aux, int n)
{
    __shared__ int s[256];
    int t = threadIdx.x;
    int base = blockIdx.x * 1024 + t * 4;
    int v[4];
    int sum = 0;
    #pragma unroll
    for (int j = 0; j < 4; ++j) {
        v[j] = (base + j < n) ? in[base + j] : 0;
        sum += v[j];
    }
    s[t] = sum;
    for (int off = 1; off < 256; off <<= 1) {
        __syncthreads();
        int u = (t >= off) ? s[t - off] : 0;
        __syncthreads();
        s[t] += u;
    }
    __syncthreads();
    int excl = (t > 0) ? s[t - 1] : 0;
    #pragma unroll
    for (int j = 0; j < 4; ++j) {
        if (base + j < n) out[base + j] = excl;
        excl += v[j];
    }
    if (t == 255) aux[blockIdx.x] = s[255];
}

// ---------------------------------------------------------------------------
// addoff2: inline scan of aux + add prefix; mirrors into cursor; writes
// the off[NR] sentinel so deg can be derived as off[i+1]-off[i].
// ---------------------------------------------------------------------------
__global__ __launch_bounds__(256) void addoff2_kernel(
    int* __restrict__ off, int* __restrict__ cursor,
    const int* __restrict__ aux, int n)
{
    __shared__ int sred[256];
    int c = blockIdx.x, t = threadIdx.x;
    if (c == 0 && t == 0) off[NR] = TOTAL_E;   // sentinel
    int part = 0;
    for (int j = t; j < c; j += 256) part += aux[j];
    sred[t] = part;
    for (int o = 128; o > 0; o >>= 1) {
        __syncthreads();
        if (t < o) sred[t] += sred[t + o];
    }
    __syncthreads();
    int S = sred[0];
    int base = c * 1024 + t * 4;
    #pragma unroll
    for (int j = 0; j < 4; ++j) {
        int i = base + j;
        if (i < n) { int v = off[i] + S; off[i] = v; cursor[i] = v; }
    }
}

// ---------------------------------------------------------------------------
// fill: sorted_src[pos] = src  (edges grouped per (rel,dst), CSR order)
// ---------------------------------------------------------------------------
__global__ __launch_bounds__(256) void fill_kernel(
    const int* __restrict__ dst, const int* __restrict__ src,
    int* __restrict__ cursor, int* __restrict__ sorted_src, int total)
{
    int i = blockIdx.x * 256 + threadIdx.x;
    if (i >= total) return;
    int rel = i / N_EDGES;
    int pos = atomicAdd(&cursor[rel * N_NODES + dst[i]], 1);
    sorted_src[pos] = src[i];
}

// ---------------------------------------------------------------------------
// Fused MFMA kernel: ONE WAVE per block, 16-row tile, 6250 blocks.
// Per rel phase: CSR gather (4 lanes/row x 32 cols, unroll x2) -> normalize
// -> bf16 -> swizzled 4KB LDS A-tile -> 32x MFMA 16x16x32 (B from L2 wT).
// All off[] ranges prefetched at start. Self-loop A direct from xb.
// Rationale: 16 concurrent row-chains per wave (vs 8 per wave before) and
// many independent 1-wave blocks -> ~3x more latency chains in flight/CU.
// ---------------------------------------------------------------------------
__global__ __launch_bounds__(64) void fused_gemm_mfma(
    const unsigned short* __restrict__ xb,   // [N,128] bf16
    const unsigned short* __restrict__ wT,   // [5,128,128] bf16 n-major
    const float* __restrict__ conv_bias,     // [4,128]
    const float* __restrict__ node_bias,     // [128]
    const int* __restrict__ off,             // [4*N + 1] (sentinel)
    const int* __restrict__ sorted_src,      // [1M]
    float* __restrict__ out)                 // [N,128] f32
{
    __shared__ __align__(16) unsigned char sIn[16 * 256];   // 4 KB

    const int lane = threadIdx.x;            // 0..63
    const int row0 = blockIdx.x * 16;
    const int l15  = lane & 15;
    const int l4   = lane >> 4;
    const int swA  = (l15 & 7) << 4;

    // gather mapping: 4 lanes/row, 32 cols (64 B) each
    const int gr  = lane >> 2;               // row 0..15
    const int gc  = lane & 3;                // col chunk: cols gc*32..+31
    const int gsw = (gr & 7) << 4;

    // prefetch all phase ranges (8 independent loads)
    int begs[4], ends[4];
    #pragma unroll
    for (int p = 0; p < 4; ++p) {
        int node = p * N_NODES + row0 + gr;
        begs[p] = off[node];
        ends[p] = off[node + 1];
    }

    f32x4 acc_mean[8];
    #pragma unroll
    for (int n = 0; n < 8; ++n) acc_mean[n] = (f32x4){0.f, 0.f, 0.f, 0.f};

    for (int phase = 0; phase < 4; ++phase) {
        __syncthreads();   // prev phase's sIn reads done (1-wave: cheap)

        // ---- CSR gather: accumulate 32 cols in regs, unroll x2 ----
        {
            int beg = begs[phase], end = ends[phase];
            const unsigned short* xcol = xb + gc * 32;
            float a[32];
            #pragma unroll
            for (int j = 0; j < 32; ++j) a[j] = 0.f;

            int e = beg;
            for (; e + 2 <= end; e += 2) {
                int s0 = sorted_src[e], s1 = sorted_src[e + 1];
                const bf16x8* p0 = reinterpret_cast<const bf16x8*>(xcol + (size_t)s0 * D);
                const bf16x8* p1 = reinterpret_cast<const bf16x8*>(xcol + (size_t)s1 * D);
                bf16x8 u0 = p0[0], u1 = p0[1], u2 = p0[2], u3 = p0[3];
                bf16x8 v0 = p1[0], v1 = p1[1], v2 = p1[2], v3 = p1[3];
                #pragma unroll
                for (int j = 0; j < 8; ++j) {
                    a[j]      += b2f(u0[j]) + b2f(v0[j]);
                    a[8 + j]  += b2f(u1[j]) + b2f(v1[j]);
                    a[16 + j] += b2f(u2[j]) + b2f(v2[j]);
                    a[24 + j] += b2f(u3[j]) + b2f(v3[j]);
                }
            }
            if (e < end) {
                int s0 = sorted_src[e];
                const bf16x8* p0 = reinterpret_cast<const bf16x8*>(xcol + (size_t)s0 * D);
                bf16x8 u0 = p0[0], u1 = p0[1], u2 = p0[2], u3 = p0[3];
                #pragma unroll
                for (int j = 0; j < 8; ++j) {
                    a[j]      += b2f(u0[j]);
                    a[8 + j]  += b2f(u1[j]);
                    a[16 + j] += b2f(u2[j]);
                    a[24 + j] += b2f(u3[j]);
                }
            }

            float scl = 1.0f / fmaxf((float)(end - beg), 1.0f);
            #pragma unroll
            for (int q = 0; q < 4; ++q) {
                bf16x8 o;
                #pragma unroll
                for (int j = 0; j < 8; ++j) o[j] = (short)f2b(a[q * 8 + j] * scl);
                *reinterpret_cast<bf16x8*>(
                    &sIn[gr * 256 + ((gc * 64 + q * 16) ^ gsw)]) = o;
            }
        }
        __syncthreads();

        // ---- MFMA: A from sIn, B from global wT (L2-resident) ----
        const unsigned short* wp = wT + (size_t)phase * D * D;
        float cb[8];
        #pragma unroll
        for (int n = 0; n < 8; ++n)
            cb[n] = conv_bias[phase * D + n * 16 + l15];

        f32x4 acc[8];
        #pragma unroll
        for (int n = 0; n < 8; ++n) acc[n] = (f32x4){0.f, 0.f, 0.f, 0.f};

        #pragma unroll
        for (int s = 0; s < 4; ++s) {
            bf16x8 a0 = *reinterpret_cast<const bf16x8*>(
                &sIn[l15 * 256 + ((s * 64 + l4 * 16) ^ swA)]);
            #pragma unroll
            for (int n = 0; n < 8; ++n) {
                bf16x8 b0 = *reinterpret_cast<const bf16x8*>(
                    wp + (n * 16 + l15) * D + s * 32 + l4 * 8);
                acc[n] = __builtin_amdgcn_mfma_f32_16x16x32_bf16(a0, b0, acc[n], 0, 0, 0);
            }
        }

        #pragma unroll
        for (int n = 0; n < 8; ++n)
            #pragma unroll
            for (int j = 0; j < 4; ++j)
                acc_mean[n][j] += 0.25f * fmaxf(acc[n][j] + cb[n], 0.f);
    }

    // ---- self-loop phase: A-frags direct from global xb ----
    f32x4 acc_self[8];
    {
        const unsigned short* wp = wT + (size_t)4 * D * D;
        float nb[8];
        #pragma unroll
        for (int n = 0; n < 8; ++n) nb[n] = node_bias[n * 16 + l15];
        #pragma unroll
        for (int n = 0; n < 8; ++n) acc_self[n] = (f32x4){0.f, 0.f, 0.f, 0.f};

        #pragma unroll
        for (int s = 0; s < 4; ++s) {
            bf16x8 a0 = *reinterpret_cast<const bf16x8*>(
                xb + (size_t)(row0 + l15) * D + s * 32 + l4 * 8);
            #pragma unroll
            for (int n = 0; n < 8; ++n) {
                bf16x8 b0 = *reinterpret_cast<const bf16x8*>(
                    wp + (n * 16 + l15) * D + s * 32 + l4 * 8);
                acc_self[n] = __builtin_amdgcn_mfma_f32_16x16x32_bf16(a0, b0, acc_self[n], 0, 0, 0);
            }
        }
        #pragma unroll
        for (int n = 0; n < 8; ++n)
            #pragma unroll
            for (int j = 0; j < 4; ++j)
                acc_self[n][j] += nb[n];
    }

    // ---- final epilogue: relu(silu(mean) + self) ----
    #pragma unroll
    for (int n = 0; n < 8; ++n)
        #pragma unroll
        for (int j = 0; j < 4; ++j) {
            float mn = acc_mean[n][j];                 // >= 0
            float sl = mn / (1.0f + __expf(-mn));
            float v  = fmaxf(sl + acc_self[n][j], 0.f);
            int row = row0 + l4 * 4 + j;
            int col = n * 16 + l15;
            out[(size_t)row * D + col] = v;
        }
}

// ---------------------------------------------------------------------------
extern "C" void kernel_launch(void* const* d_in, const int* in_sizes, int n_in,
                              void* d_out, int out_size, void* d_ws, size_t ws_size,
                              hipStream_t stream) {
    const float* x         = (const float*)d_in[0];
    const float* weight    = (const float*)d_in[1];
    const float* conv_bias = (const float*)d_in[2];
    const float* loop_w    = (const float*)d_in[3];
    const float* node_bias = (const float*)d_in[4];
    const int*   src       = (const int*)d_in[5];
    const int*   dst       = (const int*)d_in[6];
    float* out = (float*)d_out;

    // ws layout (bytes)
    char* w = (char*)d_ws;
    int* deg            = (int*)(w);                      // 1.6 MB
    int* off            = (int*)(w + 1600000);            // 1.6 MB + sentinel
    int* cursor         = (int*)(w + 3200008);            // 1.6 MB
    int* aux            = (int*)(w + 4800008);            // 2 KB
    int* sorted_src     = (int*)(w + 4802056);            // 4 MB
    unsigned short* xb  = (unsigned short*)(w + 8802056); // 25.6 MB
    unsigned short* wT  = (unsigned short*)(w + 8802056 + (size_t)N_NODES * D * 2);

    const int SCAN_BLKS = (NR + 1023) / 1024;   // 391

    hipMemsetAsync(deg, 0, NR * sizeof(int), stream);
    prep_kernel<<<PREP_X_BLKS + PREP_W_BLKS + PREP_H_BLKS, 256, 0, stream>>>(
        x, weight, loop_w, dst, xb, wT, deg);
    scan1_kernel<<<SCAN_BLKS, 256, 0, stream>>>(deg, off, aux, NR);
    addoff2_kernel<<<SCAN_BLKS, 256, 0, stream>>>(off, cursor, aux, NR);
    fill_kernel<<<(TOTAL_E + 255) / 256, 256, 0, stream>>>(
        dst, src, cursor, sorted_src, TOTAL_E);
    fused_gemm_mfma<<<N_NODES / 16, 64, 0, stream>>>(
        xb, wT, conv_bias, node_bias, off, sorted_src, out);
}